// Round 11
// baseline (609.207 us; speedup 1.0000x reference)
//
#include <hip/hip_runtime.h>
#include <hip/hip_bf16.h>

#define T_STEPS 365
#define XLEN    (T_STEPS * 3)
#define H_SZ    256
#define ROWS    16
#define NW      8      // waves per block (2 per SIMD)
#define CPW     32     // state cols per wave

#define SF1     (-1.4426950408889634f)   // -log2(e): folded into W_f, W_o
#define SF2     (-2.8853900817779268f)   // -2 log2(e): folded into W_g, tanh(c)

typedef __attribute__((ext_vector_type(8))) short bf16x8;   // 8 bf16 = 4 VGPRs
typedef __attribute__((ext_vector_type(4))) short bf16x4;   // 4 bf16 = 2 VGPRs
typedef __attribute__((ext_vector_type(4))) float f32x4;

__device__ __forceinline__ float fast_sigmoid(float x) {    // plain form (iv only)
    return __builtin_amdgcn_rcpf(1.0f + __builtin_amdgcn_exp2f(-1.44269504f * x));
}
__device__ __forceinline__ unsigned short f2bf(float x) {   // fp32 -> bf16 RTNE
    __hip_bfloat16 b = __float2bfloat16(x);
    return *reinterpret_cast<unsigned short*>(&b);
}
__device__ __forceinline__ float bf2f(unsigned short v) {
    return __uint_as_float(((unsigned)v) << 16);
}
__device__ __forceinline__ bf16x8 expand4(bf16x4 v) {       // {v0..v3,0,0,0,0}
    bf16x8 r = (bf16x8)0;
    r[0] = v[0]; r[1] = v[1]; r[2] = v[2]; r[3] = v[3];
    return r;
}
// exp2-native LSTM gate bundle (weights pre-scaled by SF1/SF2)
__device__ __forceinline__ bf16x4 do_gates(const f32x4 zf, const f32x4 zg,
                                           const f32x4 zo, const float iv[4],
                                           float cst[4]) {
    bf16x4 pk;
#pragma unroll
    for (int q = 0; q < 4; ++q) {
        const float fq = __builtin_amdgcn_rcpf(1.0f + __builtin_amdgcn_exp2f(zf[q]));
        const float gq = 2.0f * __builtin_amdgcn_rcpf(1.0f + __builtin_amdgcn_exp2f(zg[q])) - 1.0f;
        const float oq = __builtin_amdgcn_rcpf(1.0f + __builtin_amdgcn_exp2f(zo[q]));
        const float cq = fq * cst[q] + iv[q] * gq;
        cst[q] = cq;
        const float th = 2.0f * __builtin_amdgcn_rcpf(1.0f + __builtin_amdgcn_exp2f(SF2 * cq)) - 1.0f;
        pk[q] = (short)f2bf(oq * th);
    }
    return pk;
}

// pre-kernel: pack x_dyn -> d_ws as bf16 {x0,x1,x2,1.0} per (block,t,row)
__global__ void __launch_bounds__(256)
xstage(const float* __restrict__ x_dyn, unsigned short* __restrict__ xg)
{
    const int rb = blockIdx.x * ROWS;
    for (int idx = threadIdx.x; idx < T_STEPS * ROWS; idx += 256) {
        const int t = idx % T_STEPS, r = idx / T_STEPS;
        const float* s = x_dyn + (size_t)(rb + r) * XLEN + t * 3;
        bf16x4 pk;
        pk[0] = (short)f2bf(s[0]); pk[1] = (short)f2bf(s[1]);
        pk[2] = (short)f2bf(s[2]); pk[3] = (short)0x3F80;   // 1.0 bf16
        *(bf16x4*)&xg[((size_t)blockIdx.x * T_STEPS + t) * 64 + r * 4] = pk;
    }
}

// Round-11: producer/consumer wave-role pipeline.
// Waves 0-3 ("A") own h cols 0-127 (kt0-3); waves 4-7 ("B") own cols 128-255.
// seg1: A: MFMA kt0-3(t)          | B: deferred gates(t-1) + write half2(t-1)
// bar_a
// seg2: A: MFMA kt4-7+x, gates(t), write half1(t) | B: MFMA all(t) -> accB
// bar_b
// Cross-wave MFMA/trans overlap per SIMD; no intra-wave interleave needed.
__global__ void __launch_bounds__(512, 2)
ealstm_fused(const unsigned short* __restrict__ xg, const float* __restrict__ x_stat,
             const float* __restrict__ w_i, const float* __restrict__ b_i,
             const float* __restrict__ w_f, const float* __restrict__ b_f,
             const float* __restrict__ w_g, const float* __restrict__ b_g,
             const float* __restrict__ w_o, const float* __restrict__ b_o,
             const float* __restrict__ w_head, const float* __restrict__ b_head,
             float* __restrict__ out)
{
    const int tid   = threadIdx.x;
    const int lane  = tid & 63;
    const int wv    = tid >> 6;       // 0..7
    const int m     = lane & 15;      // batch row (N dim of D)
    const int l16   = lane >> 4;      // 0..3
    const int rb    = blockIdx.x * ROWS;
    const int wbase = wv * CPW;
    const bool grpA = (wv < 4);

    __shared__ unsigned short wo_lds[4 * 8 * 256 * 8];    // 128 KB [l16][kt][c][e]
    __shared__ unsigned short hbuf[2][4096];              // 16 KB h^T B-pack, dbuf
    __shared__ float          red[NW][ROWS];

    // ---- one-time staging ----
    for (int idx = tid; idx < 4 * 8 * 8 * 256; idx += 512) {
        const int c    = idx & 255;
        const int e    = (idx >> 8) & 7;
        const int kt   = (idx >> 11) & 7;
        const int l16g = idx >> 14;
        wo_lds[((l16g * 8 + kt) * 256 + c) * 8 + e] =
            f2bf(SF1 * w_o[(3 + kt * 32 + l16g * 8 + e) * H_SZ + c]);
    }
    for (int idx = tid; idx < 2048; idx += 512) ((unsigned int*)hbuf[0])[idx] = 0u;

    const float* wsrc[3] = {w_f, w_g, w_o};
    const float* bsrc[3] = {b_f, b_g, b_o};
    const float  gsf[3]  = {SF1, SF2, SF1};

    // ---- weights -> registers (pre-scaled) ----
    bf16x8 wA[8][2][2];      // f,g gates, all 8 kt = 128 regs
    bf16x4 wX[2][3];         // x/bias tile; nonzero only l16==0
#pragma unroll
    for (int ct = 0; ct < 2; ++ct) {
        const int c = wbase + ct * 16 + m;
#pragma unroll
        for (int g = 0; g < 2; ++g)
#pragma unroll
            for (int kt = 0; kt < 8; ++kt) {
                bf16x8 a;
#pragma unroll
                for (int e = 0; e < 8; ++e)
                    a[e] = (short)f2bf(gsf[g] * wsrc[g][(3 + kt * 32 + l16 * 8 + e) * H_SZ + c]);
                wA[kt][ct][g] = a;
            }
#pragma unroll
        for (int g = 0; g < 3; ++g) {
            bf16x4 ax = (bf16x4)0;
            if (l16 == 0) {
                ax[0] = (short)f2bf(gsf[g] * wsrc[g][0 * H_SZ + c]);
                ax[1] = (short)f2bf(gsf[g] * wsrc[g][1 * H_SZ + c]);
                ax[2] = (short)f2bf(gsf[g] * wsrc[g][2 * H_SZ + c]);
                ax[3] = (short)f2bf(gsf[g] * bsrc[g][c]);
            }
            wX[ct][g] = ax;
        }
    }

    // ---- static input gate (fp32 regs) + cell state ----
    float iv[2][4], cst[2][4];
    {
        const float xs0 = x_stat[(rb + m) * 3 + 0];
        const float xs1 = x_stat[(rb + m) * 3 + 1];
        const float xs2 = x_stat[(rb + m) * 3 + 2];
#pragma unroll
        for (int ct = 0; ct < 2; ++ct)
#pragma unroll
            for (int q = 0; q < 4; ++q) {
                const int c = wbase + ct * 16 + l16 * 4 + q;
                iv[ct][q] = fast_sigmoid(b_i[c] + xs0 * w_i[c] + xs1 * w_i[H_SZ + c]
                                                + xs2 * w_i[2 * H_SZ + c]);
                cst[ct][q] = 0.0f;
            }
    }

    // h-write offsets: c0 = wbase+ct*16+l16*4; kt=c0>>5; L=m+16*((c0&31)>>3); e=c0&7
    int woff[2];
#pragma unroll
    for (int ct = 0; ct < 2; ++ct) {
        const int c0 = wbase + ct * 16 + l16 * 4;
        woff[ct] = ((c0 >> 5) * 64 + m + 16 * ((c0 & 31) >> 3)) * 8 + (c0 & 7);
    }

    const unsigned short* xrow   = xg + (size_t)blockIdx.x * T_STEPS * 64 + m * 4;
    const bf16x8*         wobase = (const bf16x8*)&wo_lds[((l16 * 8) * 256 + wbase + m) * 8];

    f32x4 accB[2][3];   // B-group: acc carried across bar_b into next seg1

    __syncthreads();

    for (int t = 0; t < T_STEPS; ++t) {
        const bf16x8* hp = (const bf16x8*)hbuf[t & 1] + lane;   // h(t-1)
        unsigned short* hwW = hbuf[(t + 1) & 1];                // h(t) slot
        unsigned short* hwP = hbuf[t & 1];                      // h(t-1) slot (B late-write)

        f32x4 accA[2][3];
        bf16x8 xfA = (bf16x8)0;

        // ================= seg1 =================
        if (grpA) {
            // prefetch x(t); MFMA kt0-3 (reads half1 of h(t-1) only)
            {
                unsigned long long xv = *(const unsigned long long*)&xrow[(size_t)t * 64];
                if (l16 != 0) xv = 0ULL;
                union { unsigned long long u; bf16x4 v; } X; X.u = xv;
                xfA[0] = X.v[0]; xfA[1] = X.v[1]; xfA[2] = X.v[2]; xfA[3] = X.v[3];
            }
            const f32x4 z4 = {0.f, 0.f, 0.f, 0.f};
            bf16x8 hb0 = hp[0];
#pragma unroll
            for (int ct = 0; ct < 2; ++ct) {
                accA[ct][0] = __builtin_amdgcn_mfma_f32_16x16x32_bf16(wA[0][ct][0], hb0, z4, 0, 0, 0);
                accA[ct][1] = __builtin_amdgcn_mfma_f32_16x16x32_bf16(wA[0][ct][1], hb0, z4, 0, 0, 0);
                accA[ct][2] = __builtin_amdgcn_mfma_f32_16x16x32_bf16(wobase[ct * 16], hb0, z4, 0, 0, 0);
            }
#pragma unroll
            for (int kt = 1; kt < 4; ++kt) {
                const bf16x8 b = hp[kt * 64];
#pragma unroll
                for (int ct = 0; ct < 2; ++ct) {
                    accA[ct][0] = __builtin_amdgcn_mfma_f32_16x16x32_bf16(wA[kt][ct][0], b, accA[ct][0], 0, 0, 0);
                    accA[ct][1] = __builtin_amdgcn_mfma_f32_16x16x32_bf16(wA[kt][ct][1], b, accA[ct][1], 0, 0, 0);
                    accA[ct][2] = __builtin_amdgcn_mfma_f32_16x16x32_bf16(wobase[kt * 256 + ct * 16], b, accA[ct][2], 0, 0, 0);
                }
            }
        } else {
            if (t > 0) {   // deferred gates for step t-1; write half2(t-1)
                const bf16x4 pk0 = do_gates(accB[0][0], accB[0][1], accB[0][2], iv[0], cst[0]);
                *(bf16x4*)&hwP[woff[0]] = pk0;
                const bf16x4 pk1 = do_gates(accB[1][0], accB[1][1], accB[1][2], iv[1], cst[1]);
                *(bf16x4*)&hwP[woff[1]] = pk1;
            }
        }
        __syncthreads();   // bar_a: half2(t-1) visible; A's kt0-3 done

        // ================= seg2 =================
        if (grpA) {
#pragma unroll
            for (int kt = 4; kt < 8; ++kt) {
                const bf16x8 b = hp[kt * 64];
#pragma unroll
                for (int ct = 0; ct < 2; ++ct) {
                    accA[ct][0] = __builtin_amdgcn_mfma_f32_16x16x32_bf16(wA[kt][ct][0], b, accA[ct][0], 0, 0, 0);
                    accA[ct][1] = __builtin_amdgcn_mfma_f32_16x16x32_bf16(wA[kt][ct][1], b, accA[ct][1], 0, 0, 0);
                    accA[ct][2] = __builtin_amdgcn_mfma_f32_16x16x32_bf16(wobase[kt * 256 + ct * 16], b, accA[ct][2], 0, 0, 0);
                }
            }
#pragma unroll
            for (int ct = 0; ct < 2; ++ct)
#pragma unroll
                for (int g = 0; g < 3; ++g)
                    accA[ct][g] = __builtin_amdgcn_mfma_f32_16x16x32_bf16(
                        expand4(wX[ct][g]), xfA, accA[ct][g], 0, 0, 0);
            const bf16x4 pk0 = do_gates(accA[0][0], accA[0][1], accA[0][2], iv[0], cst[0]);
            *(bf16x4*)&hwW[woff[0]] = pk0;
            const bf16x4 pk1 = do_gates(accA[1][0], accA[1][1], accA[1][2], iv[1], cst[1]);
            *(bf16x4*)&hwW[woff[1]] = pk1;
        } else {
            bf16x8 xfB = (bf16x8)0;
            {
                unsigned long long xv = *(const unsigned long long*)&xrow[(size_t)t * 64];
                if (l16 != 0) xv = 0ULL;
                union { unsigned long long u; bf16x4 v; } X; X.u = xv;
                xfB[0] = X.v[0]; xfB[1] = X.v[1]; xfB[2] = X.v[2]; xfB[3] = X.v[3];
            }
            const f32x4 z4 = {0.f, 0.f, 0.f, 0.f};
            bf16x8 hb0 = hp[0];
#pragma unroll
            for (int ct = 0; ct < 2; ++ct) {
                accB[ct][0] = __builtin_amdgcn_mfma_f32_16x16x32_bf16(wA[0][ct][0], hb0, z4, 0, 0, 0);
                accB[ct][1] = __builtin_amdgcn_mfma_f32_16x16x32_bf16(wA[0][ct][1], hb0, z4, 0, 0, 0);
                accB[ct][2] = __builtin_amdgcn_mfma_f32_16x16x32_bf16(wobase[ct * 16], hb0, z4, 0, 0, 0);
            }
#pragma unroll
            for (int kt = 1; kt < 8; ++kt) {
                const bf16x8 b = hp[kt * 64];
#pragma unroll
                for (int ct = 0; ct < 2; ++ct) {
                    accB[ct][0] = __builtin_amdgcn_mfma_f32_16x16x32_bf16(wA[kt][ct][0], b, accB[ct][0], 0, 0, 0);
                    accB[ct][1] = __builtin_amdgcn_mfma_f32_16x16x32_bf16(wA[kt][ct][1], b, accB[ct][1], 0, 0, 0);
                    accB[ct][2] = __builtin_amdgcn_mfma_f32_16x16x32_bf16(wobase[kt * 256 + ct * 16], b, accB[ct][2], 0, 0, 0);
                }
            }
#pragma unroll
            for (int ct = 0; ct < 2; ++ct)
#pragma unroll
                for (int g = 0; g < 3; ++g)
                    accB[ct][g] = __builtin_amdgcn_mfma_f32_16x16x32_bf16(
                        expand4(wX[ct][g]), xfB, accB[ct][g], 0, 0, 0);
        }
        __syncthreads();   // bar_b: half1(t) visible
    }

    // ---- epilogue: B flushes gates(T-1) into h slot 1 ----
    if (!grpA) {
        const bf16x4 pk0 = do_gates(accB[0][0], accB[0][1], accB[0][2], iv[0], cst[0]);
        *(bf16x4*)&hbuf[1][woff[0]] = pk0;
        const bf16x4 pk1 = do_gates(accB[1][0], accB[1][1], accB[1][2], iv[1], cst[1]);
        *(bf16x4*)&hbuf[1][woff[1]] = pk1;
    }
    __syncthreads();

    // ---- head: out[r] = sum_c h[r][c] w_head[c] + b_head ----
    float p = 0.0f;
    const unsigned short* hf = hbuf[1];   // h(364) slot = (365)&1 = 1
#pragma unroll
    for (int ct = 0; ct < 2; ++ct) {
        const int c0 = wbase + ct * 16 + l16 * 4;
        const f32x4 wh = *(const f32x4*)&w_head[c0];
        const bf16x4 hv = *(const bf16x4*)&hf[woff[ct]];
#pragma unroll
        for (int q = 0; q < 4; ++q) p += bf2f((unsigned short)hv[q]) * wh[q];
    }
    p += __shfl_xor(p, 16);
    p += __shfl_xor(p, 32);
    if (lane < 16) red[wv][m] = p;
    __syncthreads();
    if (tid < ROWS) {
        float s = b_head[0];
#pragma unroll
        for (int w = 0; w < NW; ++w) s += red[w][tid];
        out[rb + tid] = s;
    }
}

extern "C" void kernel_launch(void* const* d_in, const int* in_sizes, int n_in,
                              void* d_out, int out_size, void* d_ws, size_t ws_size,
                              hipStream_t stream)
{
    const float* x_dyn  = (const float*)d_in[0];
    const float* x_stat = (const float*)d_in[1];
    const float* w_i    = (const float*)d_in[2];
    const float* b_i    = (const float*)d_in[3];
    const float* w_f    = (const float*)d_in[4];
    const float* b_f    = (const float*)d_in[5];
    const float* w_g    = (const float*)d_in[6];
    const float* b_g    = (const float*)d_in[7];
    const float* w_o    = (const float*)d_in[8];
    const float* b_o    = (const float*)d_in[9];
    const float* w_head = (const float*)d_in[10];
    const float* b_head = (const float*)d_in[11];

    unsigned short* xg = (unsigned short*)d_ws;   // 64*365*64*2 B = 2.99 MB

    xstage<<<dim3(64), dim3(256), 0, stream>>>(x_dyn, xg);
    ealstm_fused<<<dim3(64), dim3(512), 0, stream>>>(
        xg, x_stat, w_i, b_i, w_f, b_f, w_g, b_g, w_o, b_o,
        w_head, b_head, (float*)d_out);
}